// Round 6
// baseline (422.017 us; speedup 1.0000x reference)
//
#include <hip/hip_runtime.h>

// ---------------------------------------------------------------------------
// MultiheadCosformerAttention: B=4, L=4096, E=1024, H=16, hd=64
// Round 6: revert gemm_qkv to row-major epilogue (VGPR 84); move k/v
//          transpose to dedicated coalesced LDS-tile kernels; attn_mfma
//          rebuilt fully LDS-free (q and Bt frags are native 16B loads).
// ---------------------------------------------------------------------------

typedef unsigned short u16;
typedef unsigned int u32;
typedef __attribute__((ext_vector_type(8))) __bf16 bf16x8;
typedef __attribute__((ext_vector_type(4))) float f32x4;

#define PI_HALF 1.57079632679489662f
#define EPS_Z 1e-4f

__device__ __forceinline__ u16 f32_to_bf16(float f) {
    union { float f; unsigned int u; } x; x.f = f;
    unsigned int lsb = (x.u >> 16) & 1u;
    x.u += 0x7fffu + lsb;                 // round-to-nearest-even
    return (u16)(x.u >> 16);
}
__device__ __forceinline__ float bf16_to_f32(u16 u) {
    union { float f; unsigned int u; } x; x.u = ((unsigned int)u) << 16;
    return x.f;
}

typedef __attribute__((address_space(1))) void amdgpu_global_t;
typedef __attribute__((address_space(3))) void amdgpu_lds_t;
__device__ __forceinline__ void async_load16(const u16* g, u16* l) {
    __builtin_amdgcn_global_load_lds((amdgpu_global_t*)g, (amdgpu_lds_t*)l, 16, 0, 0);
}

// ---------------------------------------------------------------------------
// fp32 -> bf16 converts
// ---------------------------------------------------------------------------
__global__ __launch_bounds__(256) void cvt_bf16(const float* __restrict__ in,
                                                u16* __restrict__ out, int n4) {
    int i = blockIdx.x * 256 + threadIdx.x;
    if (i >= n4) return;
    float4 f = ((const float4*)in)[i];
    ushort4 o;
    o.x = f32_to_bf16(f.x); o.y = f32_to_bf16(f.y);
    o.z = f32_to_bf16(f.z); o.w = f32_to_bf16(f.w);
    ((ushort4*)out)[i] = o;
}

__global__ __launch_bounds__(256) void cvt_w4(const float* __restrict__ w0,
                                              const float* __restrict__ w1,
                                              const float* __restrict__ w2,
                                              const float* __restrict__ w3,
                                              u16* __restrict__ wcat) {
    const float* src = (blockIdx.y == 0) ? w0 : (blockIdx.y == 1) ? w1
                     : (blockIdx.y == 2) ? w2 : w3;
    u16* dst = wcat + (size_t)blockIdx.y * 1048576;
    int i = blockIdx.x * 256 + threadIdx.x;
    float4 f = ((const float4*)src)[i];
    ushort4 o;
    o.x = f32_to_bf16(f.x); o.y = f32_to_bf16(f.y);
    o.z = f32_to_bf16(f.z); o.w = f32_to_bf16(f.w);
    ((ushort4*)dst)[i] = o;
}

// ---------------------------------------------------------------------------
// Fused QKV GEMM (m97 structure, round-4 epilogue). Wcat=[3072][1024].
// All outputs row-major [token][1024]; relu on q,k.
// ---------------------------------------------------------------------------
__global__ __launch_bounds__(256) void gemm_qkv(const u16* __restrict__ A,
                                                const u16* __restrict__ Wcat,
                                                const float* __restrict__ bq,
                                                const float* __restrict__ bk,
                                                const float* __restrict__ bv,
                                                u16* __restrict__ qo,
                                                u16* __restrict__ ko,
                                                u16* __restrict__ vo) {
    __shared__ u16 As[128 * 32];
    __shared__ u16 Bs[128 * 32];
    const int K = 1024;
    const int tid  = threadIdx.x;
    const int wave = tid >> 6;
    const int lane = tid & 63;
    const int quad = lane >> 4;
    const int l15  = lane & 15;
    const long tileM = (long)blockIdx.x * 128;
    const long tileN = (long)blockIdx.y * 128;
    const int mat = blockIdx.y >> 3;
    const float* bias = (mat == 0) ? bq : (mat == 1) ? bk : bv;
    u16* outp = (mat == 0) ? qo : (mat == 1) ? ko : vo;
    const bool relu = (mat < 2);
    const int wm = (wave >> 1) * 64;
    const int wn = (wave & 1) * 64;
    const int s_row = wave * 32 + (lane >> 2);
    const int s_col = (lane & 3) * 8;

    const u16* gA = A    + (tileM + s_row) * (long)K + s_col;
    const u16* gB = Wcat + (tileN + s_row) * (long)K + s_col;
    u16* lA = &As[wave * 1024];
    u16* lB = &Bs[wave * 1024];

    f32x4 acc[4][4] = {};

    for (int kb = 0; kb < K; kb += 32) {
        async_load16(gA,                lA);
        async_load16(gA + 16 * (long)K, lA + 512);
        async_load16(gB,                lB);
        async_load16(gB + 16 * (long)K, lB + 512);
        gA += 32; gB += 32;
        __syncthreads();
        bf16x8 af[4], bf[4];
#pragma unroll
        for (int i = 0; i < 4; i++) {
            af[i] = *(const bf16x8*)&As[(wm + i * 16 + l15) * 32 + quad * 8];
            bf[i] = *(const bf16x8*)&Bs[(wn + i * 16 + l15) * 32 + quad * 8];
        }
#pragma unroll
        for (int i = 0; i < 4; i++)
#pragma unroll
            for (int j = 0; j < 4; j++)
                acc[i][j] = __builtin_amdgcn_mfma_f32_16x16x32_bf16(
                    af[i], bf[j], acc[i][j], 0, 0, 0);
        __syncthreads();
    }

#pragma unroll
    for (int j = 0; j < 4; j++) {
        const int nl = (int)(tileN + wn + j * 16 + l15) & 1023;
        const float bv_ = bias[nl];
#pragma unroll
        for (int i = 0; i < 4; i++) {
            const long m0 = tileM + wm + i * 16 + quad * 4;
#pragma unroll
            for (int r = 0; r < 4; r++) {
                float v = acc[i][j][r] + bv_;
                if (relu) v = fmaxf(v, 0.0f);
                outp[(m0 + r) * 1024 + nl] = f32_to_bf16(v);
            }
        }
    }
}

// ---------------------------------------------------------------------------
// Output-projection GEMM (fp32 out), m97 structure.
// ---------------------------------------------------------------------------
__global__ __launch_bounds__(256) void gemm_o(const u16* __restrict__ A,
                                              const u16* __restrict__ Bw,
                                              const float* __restrict__ bias,
                                              float* __restrict__ Cout,
                                              int M, int N, int K) {
    __shared__ u16 As[128 * 32];
    __shared__ u16 Bs[128 * 32];
    const int tid  = threadIdx.x;
    const int wave = tid >> 6;
    const int lane = tid & 63;
    const int quad = lane >> 4;
    const int l15  = lane & 15;
    const long tileM = (long)blockIdx.x * 128;
    const long tileN = (long)blockIdx.y * 128;
    const int wm = (wave >> 1) * 64;
    const int wn = (wave & 1) * 64;
    const int s_row = wave * 32 + (lane >> 2);
    const int s_col = (lane & 3) * 8;

    const u16* gA = A  + (tileM + s_row) * (long)K + s_col;
    const u16* gB = Bw + (tileN + s_row) * (long)K + s_col;
    u16* lA = &As[wave * 1024];
    u16* lB = &Bs[wave * 1024];

    f32x4 acc[4][4] = {};

    for (int kb = 0; kb < K; kb += 32) {
        async_load16(gA,                lA);
        async_load16(gA + 16 * (long)K, lA + 512);
        async_load16(gB,                lB);
        async_load16(gB + 16 * (long)K, lB + 512);
        gA += 32; gB += 32;
        __syncthreads();
        bf16x8 af[4], bf[4];
#pragma unroll
        for (int i = 0; i < 4; i++) {
            af[i] = *(const bf16x8*)&As[(wm + i * 16 + l15) * 32 + quad * 8];
            bf[i] = *(const bf16x8*)&Bs[(wn + i * 16 + l15) * 32 + quad * 8];
        }
#pragma unroll
        for (int i = 0; i < 4; i++)
#pragma unroll
            for (int j = 0; j < 4; j++)
                acc[i][j] = __builtin_amdgcn_mfma_f32_16x16x32_bf16(
                    af[i], bf[j], acc[i][j], 0, 0, 0);
        __syncthreads();
    }

#pragma unroll
    for (int j = 0; j < 4; j++) {
        const long n = tileN + wn + j * 16 + l15;
        const float bv = bias[n];
#pragma unroll
        for (int i = 0; i < 4; i++) {
            const long m0 = tileM + wm + i * 16 + quad * 4;
#pragma unroll
            for (int r = 0; r < 4; r++)
                Cout[(m0 + r) * (long)N + n] = acc[i][j][r] + bv;
        }
    }
}

// ---------------------------------------------------------------------------
// Transpose [16384 tok][1024 feat] -> [1024 feat][16384 tok], bf16.
// 64x64 tiles; LDS u32-packed (2 tokens/word), stride 33 -> bank=(d+l)%32,
// 2-way both phases (free). Coalesced 16B global loads & stores.
// grid (256, 16), 256 threads.
// ---------------------------------------------------------------------------
__global__ __launch_bounds__(256) void transpose_64(const u16* __restrict__ src,
                                                    u16* __restrict__ dst) {
    __shared__ u32 tl[64 * 33];
    const int t = threadIdx.x;
    const int tok0 = blockIdx.x * 64;
    const int f0 = blockIdx.y * 64;
    const int lp = t >> 3;            // token pair index 0..31
    const int d0 = (t & 7) * 8;       // feature octet
    const u16* s0 = src + (size_t)(tok0 + 2 * lp) * 1024 + f0 + d0;
    uint4 r0 = *(const uint4*)s0;
    uint4 r1 = *(const uint4*)(s0 + 1024);
    const u16* a = (const u16*)&r0;
    const u16* b_ = (const u16*)&r1;
#pragma unroll
    for (int e = 0; e < 8; e++)
        tl[(d0 + e) * 33 + lp] = (u32)a[e] | ((u32)b_[e] << 16);
    __syncthreads();
    const int d = t >> 2;             // feature row 0..63
    const int lg = (t & 3) * 8;       // token-pair group
    u32 o[8];
#pragma unroll
    for (int e = 0; e < 8; e++) o[e] = tl[d * 33 + lg + e];
    u16* dp = dst + (size_t)(f0 + d) * 16384 + tok0 + lg * 2;
    *(uint4*)(dp)     = *(const uint4*)&o[0];
    *(uint4*)(dp + 8) = *(const uint4*)&o[4];
}

// ---------------------------------------------------------------------------
// Stage C (MFMA, LDS-free): part[chunk16][head64][d2 128][n 80] bf16 =
//   k_^T @ [v | 1 | 0] over 256 l's. Frags load straight from kT/vT.
// ---------------------------------------------------------------------------
__global__ __launch_bounds__(256) void kv_mfma(const u16* __restrict__ kT,
                                               const u16* __restrict__ vT,
                                               u16* __restrict__ part) {
    const int tid = threadIdx.x;
    const int wave = tid >> 6, lane = tid & 63;
    const int quad = lane >> 4, l15 = lane & 15;
    const int head = blockIdx.y;
    const int b = head >> 4, h = head & 15;
    const long col0 = (long)b * 4096 + blockIdx.x * 256 + quad * 8;
    const bool use_cos = (wave >> 1) != 0;
    const int mbase = wave * 32;

    const u16* ka[2];
#pragma unroll
    for (int i = 0; i < 2; i++) {
        const int d = (mbase + i * 16 + l15) & 63;
        ka[i] = kT + (size_t)(h * 64 + d) * 16384 + col0;
    }
    const u16* va[4];
#pragma unroll
    for (int j = 0; j < 4; j++) {
        const int n = j * 16 + l15;
        va[j] = vT + (size_t)(h * 64 + n) * 16384 + col0;
    }

    float sv[8], cv[8];
#pragma unroll
    for (int e = 0; e < 8; e++) {
        float ang = (PI_HALF / 4096.0f) * (float)(blockIdx.x * 256 + quad * 8 + e + 1);
        sv[e] = sinf(ang); cv[e] = cosf(ang);
    }
    const float cD = 0.9999247018391445f;   // cos(pi/256)
    const float sD = 0.0122715382857199f;   // sin(pi/256)

    bf16x8 onesf;
#pragma unroll
    for (int e = 0; e < 8; e++)
        onesf[e] = (l15 == 0) ? (__bf16)1.0f : (__bf16)0.0f;

    f32x4 acc[2][5] = {};

    for (int kt = 0; kt < 8; kt++) {
        bf16x8 kraw[2], bfr[5];
#pragma unroll
        for (int i = 0; i < 2; i++) kraw[i] = *(const bf16x8*)(ka[i] + kt * 32);
#pragma unroll
        for (int j = 0; j < 4; j++) bfr[j] = *(const bf16x8*)(va[j] + kt * 32);
        bfr[4] = onesf;
        bf16x8 af[2];
#pragma unroll
        for (int i = 0; i < 2; i++)
#pragma unroll
            for (int e = 0; e < 8; e++)
                af[i][e] = (__bf16)((float)kraw[i][e] * (use_cos ? cv[e] : sv[e]));
#pragma unroll
        for (int i = 0; i < 2; i++)
#pragma unroll
            for (int j = 0; j < 5; j++)
                acc[i][j] = __builtin_amdgcn_mfma_f32_16x16x32_bf16(
                    af[i], bfr[j], acc[i][j], 0, 0, 0);
#pragma unroll
        for (int e = 0; e < 8; e++) {
            const float ns = sv[e] * cD + cv[e] * sD;
            cv[e] = cv[e] * cD - sv[e] * sD;
            sv[e] = ns;
        }
    }

    u16* op = part + ((size_t)blockIdx.x * 64 + head) * 10240;
#pragma unroll
    for (int i = 0; i < 2; i++)
#pragma unroll
        for (int j = 0; j < 5; j++)
#pragma unroll
            for (int r = 0; r < 4; r++)
                op[(mbase + i * 16 + quad * 4 + r) * 80 + j * 16 + l15] =
                    f32_to_bf16(acc[i][j][r]);
}

// ---------------------------------------------------------------------------
// Stage C2: sum 16 bf16 chunk-partials, transpose to Bt[head][n=80][d2=128].
// ---------------------------------------------------------------------------
__global__ __launch_bounds__(256) void kv_reduce_t(const u16* __restrict__ part,
                                                   u16* __restrict__ Bt) {
    __shared__ float accs[32 * 81];
    const int head = blockIdx.y, d2t = blockIdx.x;
    const u16* bp = part + (size_t)head * 10240 + d2t * 32 * 80;
    for (int idx = threadIdx.x; idx < 2560; idx += 256) {
        float s = 0.0f;
#pragma unroll
        for (int c = 0; c < 16; c++)
            s += bf16_to_f32(bp[(size_t)c * 655360 + idx]);
        const int d2 = idx / 80, n = idx - d2 * 80;
        accs[d2 * 81 + n] = s;
    }
    __syncthreads();
    for (int idx = threadIdx.x; idx < 2560; idx += 256) {
        const int n = idx >> 5, d2 = idx & 31;
        Bt[(size_t)head * 10240 + n * 128 + d2t * 32 + d2] =
            f32_to_bf16(accs[d2 * 81 + n]);
    }
}

// ---------------------------------------------------------------------------
// Stage D (LDS-free): attn[l, 0..79] = q_[l, 0..127] @ Bt^T; col 64 = denom.
// q frags and Bt frags are per-lane contiguous 16B in global -> direct loads,
// no LDS, no barrier. grid (32, 64), 4 waves of 32 rows each.
// ---------------------------------------------------------------------------
__global__ __launch_bounds__(256) void attn_mfma(const u16* __restrict__ qb,
                                                 const u16* __restrict__ Bt,
                                                 u16* __restrict__ merged) {
    const int tid = threadIdx.x;
    const int wave = tid >> 6, lane = tid & 63;
    const int quad = lane >> 4, l15 = lane & 15;
    const int head = blockIdx.y;
    const int b = head >> 4, h = head & 15;
    const int tm = blockIdx.x * 128;
    const long b4 = (long)b * 4096;
    const int wm = wave * 32;

    bf16x8 q0[2], q1[2];
#pragma unroll
    for (int i = 0; i < 2; i++) {
        const u16* qp = qb + (size_t)(b4 + tm + wm + i * 16 + l15) * 1024
                      + h * 64 + quad * 8;
        q0[i] = *(const bf16x8*)qp;          // cols [quad*8 .. +8)
        q1[i] = *(const bf16x8*)(qp + 32);   // cols [32+quad*8 .. +8)
    }
    float snl[2], csl[2];
#pragma unroll
    for (int i = 0; i < 2; i++) {
        const int l = tm + wm + i * 16 + l15;
        const float idx = PI_HALF * (float)(l + 1) * (1.0f / 4096.0f);
        snl[i] = sinf(idx); csl[i] = cosf(idx);
    }

    const u16* bp = Bt + (size_t)head * 10240 + quad * 8;
    f32x4 acc[2][5] = {};
#pragma unroll
    for (int kb = 0; kb < 4; kb++) {
        bf16x8 bfr[5];
#pragma unroll
        for (int j = 0; j < 5; j++)
            bfr[j] = *(const bf16x8*)(bp + (size_t)(j * 16 + l15) * 128 + kb * 32);
        bf16x8 af[2];
#pragma unroll
        for (int i = 0; i < 2; i++) {
            bf16x8 raw = (kb & 1) ? q1[i] : q0[i];
            const float s = (kb < 2) ? snl[i] : csl[i];
#pragma unroll
            for (int e = 0; e < 8; e++) af[i][e] = (__bf16)((float)raw[e] * s);
        }
#pragma unroll
        for (int i = 0; i < 2; i++)
#pragma unroll
            for (int j = 0; j < 5; j++)
                acc[i][j] = __builtin_amdgcn_mfma_f32_16x16x32_bf16(
                    af[i], bfr[j], acc[i][j], 0, 0, 0);
    }

#pragma unroll
    for (int i = 0; i < 2; i++) {
        float z[4];
#pragma unroll
        for (int r = 0; r < 4; r++) {
            const float den = __shfl(acc[i][4][r], lane & 0x30, 64);
            z[r] = 1.0f / fmaxf(den, EPS_Z);
        }
#pragma unroll
        for (int j = 0; j < 4; j++)
#pragma unroll
            for (int r = 0; r < 4; r++) {
                const int l = tm + wm + i * 16 + quad * 4 + r;
                merged[(b4 + l) * 1024 + h * 64 + j * 16 + l15] =
                    f32_to_bf16(acc[i][j][r] * z[r]);
            }
    }
}

// ---------------------------------------------------------------------------
extern "C" void kernel_launch(void* const* d_in, const int* in_sizes, int n_in,
                              void* d_out, int out_size, void* d_ws, size_t ws_size,
                              hipStream_t stream) {
    (void)in_sizes; (void)n_in; (void)out_size; (void)ws_size;
    const float* x  = (const float*)d_in[0];
    const float* Wq = (const float*)d_in[1];
    const float* bq = (const float*)d_in[2];
    const float* Wk = (const float*)d_in[3];
    const float* bk = (const float*)d_in[4];
    const float* Wv = (const float*)d_in[5];
    const float* bv = (const float*)d_in[6];
    const float* Wo = (const float*)d_in[7];
    const float* bo = (const float*)d_in[8];
    float* out = (float*)d_out;

    const int M = 16384, E = 1024;
    char* ws = (char*)d_ws;
    const size_t MB = 1048576;
    // Region plan (<= ~138 MB, proven footprint):
    //  0-32   : xb -> kTb (x dead after gemm_qkv; kT written by transpose_k)
    //  32-64  : qb (live through attn_mfma)
    //  64-96  : kb -> vTb (k dead after transpose_k) -> mergedb (vT dead after kv_mfma)
    //  96-128 : vb -> partb (v dead after transpose_v)
    //  128-136: wcat (Wq;Wk;Wv;Wo bf16)
    //  136-   : Btb (1.31 MiB)
    u16* xb   = (u16*)(ws);
    u16* qb   = (u16*)(ws + 32 * MB);
    u16* kb   = (u16*)(ws + 64 * MB);
    u16* vb   = (u16*)(ws + 96 * MB);
    u16* wcat = (u16*)(ws + 128 * MB);
    u16* wob  = wcat + 3 * (size_t)E * E;
    u16* Btb  = (u16*)(ws + 136 * MB);
    u16* kTb  = xb;
    u16* vTb  = kb;
    u16* partb = vb;
    u16* mergedb = kb;

    cvt_bf16<<<dim3(M * E / 4 / 256), dim3(256), 0, stream>>>(x, xb, M * E / 4);
    cvt_w4<<<dim3(E * E / 4 / 256, 4), dim3(256), 0, stream>>>(Wq, Wk, Wv, Wo, wcat);

    gemm_qkv<<<dim3(M / 128, 24), dim3(256), 0, stream>>>(xb, wcat, bq, bk, bv,
                                                          qb, kb, vb);

    transpose_64<<<dim3(256, 16), dim3(256), 0, stream>>>(kb, kTb);
    transpose_64<<<dim3(256, 16), dim3(256), 0, stream>>>(vb, vTb);

    kv_mfma<<<dim3(16, 64), dim3(256), 0, stream>>>(kTb, vTb, partb);
    kv_reduce_t<<<dim3(4, 64), dim3(256), 0, stream>>>(partb, Btb);
    attn_mfma<<<dim3(32, 64), dim3(256), 0, stream>>>(qb, Btb, mergedb);

    gemm_o<<<dim3(M / 128, E / 128), dim3(256), 0, stream>>>(mergedb, wob, bo,
                                                             out, M, E, E);
}